// Round 2
// baseline (237.049 us; speedup 1.0000x reference)
//
#include <hip/hip_runtime.h>
#include <hip/hip_bf16.h>

#define N_ATOMS 32768

typedef __attribute__((ext_vector_type(4))) float f32x4;
typedef __attribute__((ext_vector_type(8))) short bf16x8;

__device__ __forceinline__ unsigned short f2b(float f) {
    union { __hip_bfloat16 b; unsigned short u; } c;
    c.b = __float2bfloat16(f);
    return c.u;
}
__device__ __forceinline__ float b2f(unsigned short u) {
    union { unsigned int i; float f; } c;
    c.i = ((unsigned int)u) << 16;
    return c.f;
}

#define GLDS16(src, dst) __builtin_amdgcn_global_load_lds( \
    (const __attribute__((address_space(1))) void*)(src),  \
    (__attribute__((address_space(3))) void*)(dst), 16, 0, 0)

// ---------------- conversion kernels ----------------

// inv_features f32 [32768,256] -> split bf16 (hi, lo), 8 elems/thread
__global__ void convx_kernel(const float* __restrict__ x,
                             unsigned short* __restrict__ xhi,
                             unsigned short* __restrict__ xlo) {
    size_t i = (size_t)(blockIdx.x * 256 + threadIdx.x) * 8;
    float4 v0 = *(const float4*)(x + i);
    float4 v1 = *(const float4*)(x + i + 4);
    float v[8] = {v0.x, v0.y, v0.z, v0.w, v1.x, v1.y, v1.z, v1.w};
    bf16x8 rh, rl;
#pragma unroll
    for (int j = 0; j < 8; ++j) {
        unsigned short h = f2b(v[j]);
        rh[j] = (short)h;
        rl[j] = (short)f2b(v[j] - b2f(h));
    }
    *(bf16x8*)(xhi + i) = rh;
    *(bf16x8*)(xlo + i) = rl;
}

// weight transposes. lat weights -> split hi/lo bf16; ro weights -> plain bf16.
__global__ void convw_kernel(const float* __restrict__ w1l, const float* __restrict__ w2l,
                             const float* __restrict__ w3l, const float* __restrict__ w1r,
                             const float* __restrict__ w2r,
                             unsigned short* __restrict__ W1LThi, unsigned short* __restrict__ W1LTlo,
                             unsigned short* __restrict__ W1RT,
                             unsigned short* __restrict__ W2LThi, unsigned short* __restrict__ W2LTlo,
                             unsigned short* __restrict__ W2RT,
                             unsigned short* __restrict__ W3LThi, unsigned short* __restrict__ W3LTlo) {
    int i = blockIdx.x * 256 + threadIdx.x;
    if (i < 131072) {                       // w1_lat [256,512] -> [512][256] hi/lo
        int n = i >> 8, k = i & 255;
        float v = w1l[k * 512 + n];
        unsigned short h = f2b(v);
        W1LThi[i] = h;
        W1LTlo[i] = f2b(v - b2f(h));
    } else if (i < 262144) {                // w1_ro [256,512] -> [512][256] bf16
        int j = i - 131072;
        int n = j >> 8, k = j & 255;
        W1RT[j] = f2b(w1r[k * 512 + n]);
    } else if (i < 524288) {                // w2_lat [512,512] -> [512][512] hi/lo
        int j = i - 262144;
        int n = j >> 9, k = j & 511;
        float v = w2l[k * 512 + n];
        unsigned short h = f2b(v);
        W2LThi[j] = h;
        W2LTlo[j] = f2b(v - b2f(h));
    } else if (i < 786432) {                // w2_ro [512,512] -> [512][512] bf16
        int j = i - 524288;
        int n = j >> 9, k = j & 511;
        W2RT[j] = f2b(w2r[k * 512 + n]);
    } else if (i < 851968) {                // w3_lat [512,128] -> [128][512] hi/lo
        int j = i - 786432;
        int n = j >> 9, k = j & 511;
        float v = w3l[k * 128 + n];
        unsigned short h = f2b(v);
        W3LThi[j] = h;
        W3LTlo[j] = f2b(v - b2f(h));
    }
}

// ---------------- plain bf16 MFMA GEMM (ro branch) ----------------
// C = silu( scale * A @ Bt^T ), 128x128 tile, 4 waves (2x2), BK=32.
template<bool SILU, bool OUT_BF16>
__global__ void __launch_bounds__(256) gemm_bf16(
        const unsigned short* __restrict__ A, int lda,
        const unsigned short* __restrict__ Bt,
        void* __restrict__ C, int ldc, int K, float scale) {
    __shared__ __align__(16) unsigned short lA[128 * 32];
    __shared__ __align__(16) unsigned short lB[128 * 32];
    const int tid = threadIdx.x;
    const int lane = tid & 63;
    const int wid = tid >> 6;
    const int wr = wid >> 1, wc = wid & 1;
    const int bn = blockIdx.x * 128;
    const int bm = blockIdx.y * 128;
    const int rlane = lane & 15;
    const int kc = lane >> 4;

    f32x4 acc[4][4] = {};

    for (int k0 = 0; k0 < K; k0 += 32) {
        __syncthreads();
#pragma unroll
        for (int call = 0; call < 2; ++call) {
            int id = call * 256 + tid;
            int row = id >> 2, cp = id & 3;
            int c = cp ^ (row & 3);   // pre-swizzled global source, linear LDS dest
            GLDS16(A + (size_t)(bm + row) * lda + (k0 + c * 8), &lA[id * 8]);
            GLDS16(Bt + (size_t)(bn + row) * K + (k0 + c * 8), &lB[id * 8]);
        }
        __syncthreads();

        bf16x8 af[4], bfr[4];
#pragma unroll
        for (int m = 0; m < 4; ++m) {
            int row = wr * 64 + m * 16 + rlane;
            int cp = kc ^ (row & 3);
            af[m] = *(const bf16x8*)&lA[row * 32 + cp * 8];
        }
#pragma unroll
        for (int n = 0; n < 4; ++n) {
            int row = wc * 64 + n * 16 + rlane;
            int cp = kc ^ (row & 3);
            bfr[n] = *(const bf16x8*)&lB[row * 32 + cp * 8];
        }
#pragma unroll
        for (int m = 0; m < 4; ++m)
#pragma unroll
            for (int n = 0; n < 4; ++n)
                acc[m][n] = __builtin_amdgcn_mfma_f32_16x16x32_bf16(af[m], bfr[n], acc[m][n], 0, 0, 0);
    }

#pragma unroll
    for (int m = 0; m < 4; ++m) {
        int grow0 = bm + wr * 64 + m * 16 + ((lane >> 4) << 2);
#pragma unroll
        for (int n = 0; n < 4; ++n) {
            int gcol = bn + wc * 64 + n * 16 + rlane;
#pragma unroll
            for (int r = 0; r < 4; ++r) {
                float v = acc[m][n][r] * scale;
                if constexpr (SILU) v = v / (1.0f + __expf(-v));
                size_t idx = (size_t)(grow0 + r) * ldc + gcol;
                if constexpr (OUT_BF16) ((unsigned short*)C)[idx] = f2b(v);
                else                    ((float*)C)[idx] = v;
            }
        }
    }
}

// ---------------- split-bf16 MFMA GEMM (lat branch, ~f32 precision) ----------------
// A ~ Ahi+Alo, B ~ Bhi+Blo; acc += Ahi*Bhi + Ahi*Blo + Alo*Bhi (drop lo*lo, ~2^-16 rel).
template<bool SILU, bool SPLIT_OUT>
__global__ void __launch_bounds__(256) gemm_split(
        const unsigned short* __restrict__ Ahi, const unsigned short* __restrict__ Alo, int lda,
        const unsigned short* __restrict__ Bthi, const unsigned short* __restrict__ Btlo,
        void* __restrict__ Chi, void* __restrict__ Clo, int ldc, int K, float scale) {
    __shared__ __align__(16) unsigned short lAhi[128 * 32];
    __shared__ __align__(16) unsigned short lAlo[128 * 32];
    __shared__ __align__(16) unsigned short lBhi[128 * 32];
    __shared__ __align__(16) unsigned short lBlo[128 * 32];
    const int tid = threadIdx.x;
    const int lane = tid & 63;
    const int wid = tid >> 6;
    const int wr = wid >> 1, wc = wid & 1;
    const int bn = blockIdx.x * 128;
    const int bm = blockIdx.y * 128;
    const int rlane = lane & 15;
    const int kc = lane >> 4;

    f32x4 acc[4][4] = {};

    for (int k0 = 0; k0 < K; k0 += 32) {
        __syncthreads();
#pragma unroll
        for (int call = 0; call < 2; ++call) {
            int id = call * 256 + tid;
            int row = id >> 2, cp = id & 3;
            int c = cp ^ (row & 3);
            size_t offA = (size_t)(bm + row) * lda + (k0 + c * 8);
            size_t offB = (size_t)(bn + row) * K + (k0 + c * 8);
            GLDS16(Ahi + offA, &lAhi[id * 8]);
            GLDS16(Alo + offA, &lAlo[id * 8]);
            GLDS16(Bthi + offB, &lBhi[id * 8]);
            GLDS16(Btlo + offB, &lBlo[id * 8]);
        }
        __syncthreads();

        bf16x8 ah[4], al[4], bh[4], bl[4];
#pragma unroll
        for (int m = 0; m < 4; ++m) {
            int row = wr * 64 + m * 16 + rlane;
            int cp = kc ^ (row & 3);
            ah[m] = *(const bf16x8*)&lAhi[row * 32 + cp * 8];
            al[m] = *(const bf16x8*)&lAlo[row * 32 + cp * 8];
        }
#pragma unroll
        for (int n = 0; n < 4; ++n) {
            int row = wc * 64 + n * 16 + rlane;
            int cp = kc ^ (row & 3);
            bh[n] = *(const bf16x8*)&lBhi[row * 32 + cp * 8];
            bl[n] = *(const bf16x8*)&lBlo[row * 32 + cp * 8];
        }
#pragma unroll
        for (int m = 0; m < 4; ++m)
#pragma unroll
            for (int n = 0; n < 4; ++n) {
                acc[m][n] = __builtin_amdgcn_mfma_f32_16x16x32_bf16(ah[m], bh[n], acc[m][n], 0, 0, 0);
                acc[m][n] = __builtin_amdgcn_mfma_f32_16x16x32_bf16(ah[m], bl[n], acc[m][n], 0, 0, 0);
                acc[m][n] = __builtin_amdgcn_mfma_f32_16x16x32_bf16(al[m], bh[n], acc[m][n], 0, 0, 0);
            }
    }

#pragma unroll
    for (int m = 0; m < 4; ++m) {
        int grow0 = bm + wr * 64 + m * 16 + ((lane >> 4) << 2);
#pragma unroll
        for (int n = 0; n < 4; ++n) {
            int gcol = bn + wc * 64 + n * 16 + rlane;
#pragma unroll
            for (int r = 0; r < 4; ++r) {
                float v = acc[m][n][r] * scale;
                if constexpr (SILU) v = v / (1.0f + __expf(-v));
                size_t idx = (size_t)(grow0 + r) * ldc + gcol;
                if constexpr (SPLIT_OUT) {
                    unsigned short h = f2b(v);
                    ((unsigned short*)Chi)[idx] = h;
                    ((unsigned short*)Clo)[idx] = f2b(v - b2f(h));
                } else {
                    ((float*)Chi)[idx] = v;
                }
            }
        }
    }
}

// ---------------- inv_out: H2R [32768,512] bf16 @ w3_ro [512,2] f32 ----------------
__global__ void invout_kernel(const unsigned short* __restrict__ H2b,
                              const float* __restrict__ w3,
                              float* __restrict__ out) {
    int g = blockIdx.x * 256 + threadIdx.x;
    int n = g >> 6;
    int lane = g & 63;
    bf16x8 hv = *(const bf16x8*)(H2b + (size_t)n * 512 + lane * 8);
    float s0 = 0.f, s1 = 0.f;
#pragma unroll
    for (int j = 0; j < 8; ++j) {
        float hf = b2f((unsigned short)hv[j]);
        int k = lane * 8 + j;
        s0 = fmaf(hf, w3[2 * k], s0);
        s1 = fmaf(hf, w3[2 * k + 1], s1);
    }
#pragma unroll
    for (int off = 32; off > 0; off >>= 1) {
        s0 += __shfl_xor(s0, off);
        s1 += __shfl_xor(s1, off);
    }
    if (lane == 0) {
        const float s = 0.04419417382415922f;   // 1/sqrt(512)
        out[2 * n] = s0 * s;
        out[2 * n + 1] = s1 * s;
    }
}

// ---------------- per-atom equivariant output ----------------
__global__ void eq_kernel(const float* __restrict__ eqf, const float* __restrict__ wgt,
                          const int* __restrict__ types, const float* __restrict__ bond,
                          float* __restrict__ out) {
    int t = blockIdx.x * 256 + threadIdx.x;   // 131072 = 32768*4
    int n = t >> 2, v = t & 3;
    const float* e = eqf + (size_t)n * 96;
    const float* w = wgt + (size_t)n * 128 + v;
    float a0 = 0.f, a1 = 0.f, a2 = 0.f;
#pragma unroll
    for (int u = 0; u < 32; ++u) {
        float wv = w[u * 4];
        a0 = fmaf(e[u * 3 + 0], wv, a0);
        a1 = fmaf(e[u * 3 + 1], wv, a1);
        a2 = fmaf(e[u * 3 + 2], wv, a2);
    }
    const float s = 0.17677669529663687f;   // 1/sqrt(32)
    a0 *= s; a1 *= s; a2 *= s;
    float norm = sqrtf(a0 * a0 + a1 * a1 + a2 * a2) + 1e-10f;
    float bl = bond[types[n] * 4 + v];
    float r0 = a0 / norm, r1 = a1 / norm, r2 = a2 / norm;
    if (isnan(r0)) r0 = 0.f;
    if (isnan(r1)) r1 = 0.f;
    if (isnan(r2)) r2 = 0.f;
    out[(size_t)n * 12 + v * 3 + 0] = r0 * bl;
    out[(size_t)n * 12 + v * 3 + 1] = r1 * bl;
    out[(size_t)n * 12 + v * 3 + 2] = r2 * bl;
}

// ---------------- launcher ----------------
extern "C" void kernel_launch(void* const* d_in, const int* in_sizes, int n_in,
                              void* d_out, int out_size, void* d_ws, size_t ws_size,
                              hipStream_t stream) {
    const float* inv  = (const float*)d_in[0];
    const float* eqf  = (const float*)d_in[1];
    const int*   typs = (const int*)d_in[2];
    const float* w1l  = (const float*)d_in[3];
    const float* w2l  = (const float*)d_in[4];
    const float* w3l  = (const float*)d_in[5];
    const float* w1r  = (const float*)d_in[6];
    const float* w2r  = (const float*)d_in[7];
    const float* w3r  = (const float*)d_in[8];
    const float* bond = (const float*)d_in[9];

    char* ws = (char*)d_ws;
    const size_t MB = 1024 * 1024, KB = 1024;
    // live-range-aliased memory map (~163 MB total):
    unsigned short* XHI   = (unsigned short*)(ws);            // 16MB [32768][256]
    unsigned short* XLO   = (unsigned short*)(ws + 16 * MB);  // 16MB
    unsigned short* H1R   = (unsigned short*)(ws + 32 * MB);  // 32MB [32768][512]
    unsigned short* H1Lhi = (unsigned short*)(ws + 64 * MB);  // 32MB
    unsigned short* H1Llo = (unsigned short*)(ws + 96 * MB);  // 32MB
    unsigned short* H2R   = (unsigned short*)(ws + 128 * MB); // 32MB
    unsigned short* H2Lhi = (unsigned short*)(ws);            // 32MB, aliases XHI+XLO (dead)
    unsigned short* H2Llo = (unsigned short*)(ws + 32 * MB);  // 32MB, aliases H1R (dead)
    float*          WGT   = (float*)(ws + 64 * MB);           // 16MB, aliases H1Lhi (dead)
    char* wb = ws + 160 * MB;
    unsigned short* W1LThi = (unsigned short*)(wb);              // 256KB [512][256]
    unsigned short* W1LTlo = (unsigned short*)(wb + 256 * KB);   // 256KB
    unsigned short* W1RT   = (unsigned short*)(wb + 512 * KB);   // 256KB
    unsigned short* W2LThi = (unsigned short*)(wb + 768 * KB);   // 512KB [512][512]
    unsigned short* W2LTlo = (unsigned short*)(wb + 1280 * KB);  // 512KB
    unsigned short* W2RT   = (unsigned short*)(wb + 1792 * KB);  // 512KB
    unsigned short* W3LThi = (unsigned short*)(wb + 2304 * KB);  // 128KB [128][512]
    unsigned short* W3LTlo = (unsigned short*)(wb + 2432 * KB);  // 128KB

    float* out_inv = (float*)d_out;                 // [32768][2]
    float* out_eq  = (float*)d_out + N_ATOMS * 2;   // [32768][4][3]

    const float s256 = 0.0625f;                 // 1/sqrt(256)
    const float s512 = 0.04419417382415922f;    // 1/sqrt(512)

    convx_kernel<<<dim3(4096), dim3(256), 0, stream>>>(inv, XHI, XLO);
    convw_kernel<<<dim3(3328), dim3(256), 0, stream>>>(w1l, w2l, w3l, w1r, w2r,
        W1LThi, W1LTlo, W1RT, W2LThi, W2LTlo, W2RT, W3LThi, W3LTlo);

    // lat L1 (split): [32768,256] @ [256,512] -> H1L hi/lo (silu)
    gemm_split<true, true><<<dim3(4, 256), dim3(256), 0, stream>>>(
        XHI, XLO, 256, W1LThi, W1LTlo, H1Lhi, H1Llo, 512, 256, s256);
    // ro L1 (bf16): [32768,256] @ [256,512] -> H1R (silu)
    gemm_bf16<true, true><<<dim3(4, 256), dim3(256), 0, stream>>>(
        XHI, 256, W1RT, H1R, 512, 256, s256);
    // ro L2 (bf16): -> H2R (silu)   [before L2-lat: H2Llo aliases H1R]
    gemm_bf16<true, true><<<dim3(4, 256), dim3(256), 0, stream>>>(
        H1R, 512, W2RT, H2R, 512, 512, s512);
    // lat L2 (split): -> H2L hi/lo (silu)
    gemm_split<true, true><<<dim3(4, 256), dim3(256), 0, stream>>>(
        H1Lhi, H1Llo, 512, W2LThi, W2LTlo, H2Lhi, H2Llo, 512, 512, s512);
    // lat L3 (split): [32768,512] @ [512,128] -> WGT f32 (no act)
    gemm_split<false, false><<<dim3(1, 256), dim3(256), 0, stream>>>(
        H2Lhi, H2Llo, 512, W3LThi, W3LTlo, WGT, nullptr, 128, 512, s512);
    // ro L3: -> out_inv
    invout_kernel<<<dim3(8192), dim3(256), 0, stream>>>(H2R, w3r, out_inv);
    // equivariant epilogue
    eq_kernel<<<dim3(512), dim3(256), 0, stream>>>(eqf, WGT, typs, bond, out_eq);
}

// Round 3
// 216.426 us; speedup vs baseline: 1.0953x; 1.0953x over previous
//
#include <hip/hip_runtime.h>
#include <hip/hip_bf16.h>

#define N_ATOMS 32768

typedef __attribute__((ext_vector_type(4))) float f32x4;
typedef __attribute__((ext_vector_type(8))) short bf16x8;
typedef unsigned short u16;

__device__ __forceinline__ u16 f2b(float f) {
    union { __hip_bfloat16 b; u16 u; } c;
    c.b = __float2bfloat16(f);
    return c.u;
}
__device__ __forceinline__ float b2f(u16 u) {
    union { unsigned int i; float f; } c;
    c.i = ((unsigned int)u) << 16;
    return c.f;
}

#define GLDS16(src, dst) __builtin_amdgcn_global_load_lds( \
    (const __attribute__((address_space(1))) void*)(src),  \
    (__attribute__((address_space(3))) void*)(dst), 16, 0, 0)

// ---------------- conversion kernels ----------------

__global__ void convx_kernel(const float* __restrict__ x,
                             u16* __restrict__ xhi, u16* __restrict__ xlo) {
    size_t i = (size_t)(blockIdx.x * 256 + threadIdx.x) * 8;
    float4 v0 = *(const float4*)(x + i);
    float4 v1 = *(const float4*)(x + i + 4);
    float v[8] = {v0.x, v0.y, v0.z, v0.w, v1.x, v1.y, v1.z, v1.w};
    bf16x8 rh, rl;
#pragma unroll
    for (int j = 0; j < 8; ++j) {
        u16 h = f2b(v[j]);
        rh[j] = (short)h;
        rl[j] = (short)f2b(v[j] - b2f(h));
    }
    *(bf16x8*)(xhi + i) = rh;
    *(bf16x8*)(xlo + i) = rl;
}

__global__ void convw_kernel(const float* __restrict__ w1l, const float* __restrict__ w2l,
                             const float* __restrict__ w3l, const float* __restrict__ w1r,
                             const float* __restrict__ w2r,
                             u16* __restrict__ W1LThi, u16* __restrict__ W1LTlo,
                             u16* __restrict__ W1RT,
                             u16* __restrict__ W2LThi, u16* __restrict__ W2LTlo,
                             u16* __restrict__ W2RT,
                             u16* __restrict__ W3LThi, u16* __restrict__ W3LTlo) {
    int i = blockIdx.x * 256 + threadIdx.x;
    if (i < 131072) {                       // w1_lat [256,512] -> [512][256] hi/lo
        int n = i >> 8, k = i & 255;
        float v = w1l[k * 512 + n];
        u16 h = f2b(v);
        W1LThi[i] = h;
        W1LTlo[i] = f2b(v - b2f(h));
    } else if (i < 262144) {                // w1_ro -> [512][256] bf16
        int j = i - 131072;
        int n = j >> 8, k = j & 255;
        W1RT[j] = f2b(w1r[k * 512 + n]);
    } else if (i < 524288) {                // w2_lat [512,512] -> hi/lo
        int j = i - 262144;
        int n = j >> 9, k = j & 511;
        float v = w2l[k * 512 + n];
        u16 h = f2b(v);
        W2LThi[j] = h;
        W2LTlo[j] = f2b(v - b2f(h));
    } else if (i < 786432) {                // w2_ro -> bf16
        int j = i - 524288;
        int n = j >> 9, k = j & 511;
        W2RT[j] = f2b(w2r[k * 512 + n]);
    } else if (i < 851968) {                // w3_lat [512,128] -> [128][512] hi/lo
        int j = i - 786432;
        int n = j >> 9, k = j & 511;
        float v = w3l[k * 128 + n];
        u16 h = f2b(v);
        W3LThi[j] = h;
        W3LTlo[j] = f2b(v - b2f(h));
    }
}

// ---------------- unified multi-segment MFMA GEMM ----------------
// C = act( scale * sum_seg Aseg @ Bseg^T ), 128x128 tile, BK=64, 4 waves (2x2),
// double-buffered LDS + counted vmcnt(8) prefetch, 8-slot XOR swizzle, XCD swizzle.
// NSEG=3: segments (Ahi,Bhi),(Alo,Bhi),(Ahi,Blo)  -- split-bf16 ~f32 precision.
// NSEG=1: plain bf16 (Ahi,Bhi).
// OUTK: 0 = f32, 1 = bf16, 2 = split hi/lo bf16.
template<int NSEG, int GX, bool SILU, int OUTK>
__global__ void __launch_bounds__(256, 2) gemm_multi(
        const u16* __restrict__ Ahi, const u16* __restrict__ Alo,
        const u16* __restrict__ Bhi, const u16* __restrict__ Blo,
        void* __restrict__ Chi, void* __restrict__ Clo,
        int ldc, int K, float scale) {
    __shared__ __align__(16) u16 lA[2][128 * 64];
    __shared__ __align__(16) u16 lB[2][128 * 64];
    const int tid = threadIdx.x;
    const int lane = tid & 63;
    const int wid = tid >> 6;
    const int wr = wid >> 1, wc = wid & 1;
    const int rlane = lane & 15;
    const int kc = lane >> 4;

    // bijective XCD swizzle (all our grids are %8==0): XCD x gets a contiguous wg chunk
    const int nwg = gridDim.x;
    const int bid = blockIdx.x;
    const int wg = (bid & 7) * (nwg >> 3) + (bid >> 3);
    const int bn = (wg % GX) * 128;
    const int bm = (wg / GX) * 128;

    const int kt = K >> 6;          // 64-wide k-tiles per segment
    const int NT = NSEG * kt;

    auto stage = [&](int t, int buf) {
        int seg = (NSEG == 1) ? 0 : ((t >= kt) + (t >= 2 * kt));
        const u16* As = (NSEG == 1) ? Ahi : (seg == 1 ? Alo : Ahi);
        const u16* Bs = (NSEG == 1) ? Bhi : (seg == 2 ? Blo : Bhi);
        int k0 = (t - seg * kt) << 6;
        u16* la = lA[buf];
        u16* lb = lB[buf];
#pragma unroll
        for (int call = 0; call < 4; ++call) {
            int id = call * 256 + tid;
            int row = id >> 3, cp = id & 7;
            int c = cp ^ (row & 7);   // pre-swizzled global source, linear LDS dest
            GLDS16(As + (size_t)(bm + row) * K + k0 + c * 8, la + id * 8);
            GLDS16(Bs + (size_t)(bn + row) * K + k0 + c * 8, lb + id * 8);
        }
    };

    f32x4 acc[4][4] = {};

    auto compute = [&](int buf) {
        const u16* la = lA[buf];
        const u16* lb = lB[buf];
        bf16x8 af[2][4], bfr[2][4];
#pragma unroll
        for (int ks = 0; ks < 2; ++ks) {
#pragma unroll
            for (int m = 0; m < 4; ++m) {
                int row = wr * 64 + m * 16 + rlane;
                int cp = (ks * 4 + kc) ^ (row & 7);
                af[ks][m] = *(const bf16x8*)&la[row * 64 + cp * 8];
            }
#pragma unroll
            for (int n = 0; n < 4; ++n) {
                int row = wc * 64 + n * 16 + rlane;
                int cp = (ks * 4 + kc) ^ (row & 7);
                bfr[ks][n] = *(const bf16x8*)&lb[row * 64 + cp * 8];
            }
        }
#pragma unroll
        for (int m = 0; m < 4; ++m)
#pragma unroll
            for (int n = 0; n < 4; ++n) {
                acc[m][n] = __builtin_amdgcn_mfma_f32_16x16x32_bf16(af[0][m], bfr[0][n], acc[m][n], 0, 0, 0);
                acc[m][n] = __builtin_amdgcn_mfma_f32_16x16x32_bf16(af[1][m], bfr[1][n], acc[m][n], 0, 0, 0);
            }
    };

    stage(0, 0);
    for (int t = 0; t < NT - 1; ++t) {
        __builtin_amdgcn_s_barrier();              // prev compute's ds_reads done -> safe to overwrite
        stage(t + 1, (t + 1) & 1);                 // next tile's loads go in flight
        __builtin_amdgcn_sched_barrier(0);         // pin loads above the counted wait
        asm volatile("s_waitcnt vmcnt(8)" ::: "memory");   // tile t's 8 loads arrived (t+1's stay in flight)
        __builtin_amdgcn_s_barrier();
        __builtin_amdgcn_sched_barrier(0);         // pin ds_reads below the barrier
        compute(t & 1);
    }
    asm volatile("s_waitcnt vmcnt(0)" ::: "memory");
    __builtin_amdgcn_s_barrier();
    __builtin_amdgcn_sched_barrier(0);
    compute((NT - 1) & 1);

    // epilogue: C/D layout col = lane&15, row = (lane>>4)*4 + reg
#pragma unroll
    for (int m = 0; m < 4; ++m) {
        int grow0 = bm + wr * 64 + m * 16 + ((lane >> 4) << 2);
#pragma unroll
        for (int n = 0; n < 4; ++n) {
            int gcol = bn + wc * 64 + n * 16 + rlane;
#pragma unroll
            for (int r = 0; r < 4; ++r) {
                float v = acc[m][n][r] * scale;
                if constexpr (SILU) v = v / (1.0f + __expf(-v));
                size_t idx = (size_t)(grow0 + r) * ldc + gcol;
                if constexpr (OUTK == 0) {
                    ((float*)Chi)[idx] = v;
                } else if constexpr (OUTK == 1) {
                    ((u16*)Chi)[idx] = f2b(v);
                } else {
                    u16 h = f2b(v);
                    ((u16*)Chi)[idx] = h;
                    ((u16*)Clo)[idx] = f2b(v - b2f(h));
                }
            }
        }
    }
}

// ---------------- inv_out: H2R [32768,512] bf16 @ w3_ro [512,2] f32 ----------------
__global__ void invout_kernel(const u16* __restrict__ H2b,
                              const float* __restrict__ w3,
                              float* __restrict__ out) {
    int g = blockIdx.x * 256 + threadIdx.x;
    int n = g >> 6;
    int lane = g & 63;
    bf16x8 hv = *(const bf16x8*)(H2b + (size_t)n * 512 + lane * 8);
    float s0 = 0.f, s1 = 0.f;
#pragma unroll
    for (int j = 0; j < 8; ++j) {
        float hf = b2f((u16)hv[j]);
        int k = lane * 8 + j;
        s0 = fmaf(hf, w3[2 * k], s0);
        s1 = fmaf(hf, w3[2 * k + 1], s1);
    }
#pragma unroll
    for (int off = 32; off > 0; off >>= 1) {
        s0 += __shfl_xor(s0, off);
        s1 += __shfl_xor(s1, off);
    }
    if (lane == 0) {
        const float s = 0.04419417382415922f;   // 1/sqrt(512)
        out[2 * n] = s0 * s;
        out[2 * n + 1] = s1 * s;
    }
}

// ---------------- per-atom equivariant output ----------------
__global__ void eq_kernel(const float* __restrict__ eqf, const float* __restrict__ wgt,
                          const int* __restrict__ types, const float* __restrict__ bond,
                          float* __restrict__ out) {
    int t = blockIdx.x * 256 + threadIdx.x;   // 131072 = 32768*4
    int n = t >> 2, v = t & 3;
    const float* e = eqf + (size_t)n * 96;
    const float* w = wgt + (size_t)n * 128 + v;
    float a0 = 0.f, a1 = 0.f, a2 = 0.f;
#pragma unroll
    for (int u = 0; u < 32; ++u) {
        float wv = w[u * 4];
        a0 = fmaf(e[u * 3 + 0], wv, a0);
        a1 = fmaf(e[u * 3 + 1], wv, a1);
        a2 = fmaf(e[u * 3 + 2], wv, a2);
    }
    const float s = 0.17677669529663687f;   // 1/sqrt(32)
    a0 *= s; a1 *= s; a2 *= s;
    float norm = sqrtf(a0 * a0 + a1 * a1 + a2 * a2) + 1e-10f;
    float bl = bond[types[n] * 4 + v];
    float r0 = a0 / norm, r1 = a1 / norm, r2 = a2 / norm;
    if (isnan(r0)) r0 = 0.f;
    if (isnan(r1)) r1 = 0.f;
    if (isnan(r2)) r2 = 0.f;
    out[(size_t)n * 12 + v * 3 + 0] = r0 * bl;
    out[(size_t)n * 12 + v * 3 + 1] = r1 * bl;
    out[(size_t)n * 12 + v * 3 + 2] = r2 * bl;
}

// ---------------- launcher ----------------
extern "C" void kernel_launch(void* const* d_in, const int* in_sizes, int n_in,
                              void* d_out, int out_size, void* d_ws, size_t ws_size,
                              hipStream_t stream) {
    const float* inv  = (const float*)d_in[0];
    const float* eqf  = (const float*)d_in[1];
    const int*   typs = (const int*)d_in[2];
    const float* w1l  = (const float*)d_in[3];
    const float* w2l  = (const float*)d_in[4];
    const float* w3l  = (const float*)d_in[5];
    const float* w1r  = (const float*)d_in[6];
    const float* w2r  = (const float*)d_in[7];
    const float* w3r  = (const float*)d_in[8];
    const float* bond = (const float*)d_in[9];

    char* ws = (char*)d_ws;
    const size_t MB = 1024 * 1024, KB = 1024;
    // live-range-aliased memory map:
    u16* XHI   = (u16*)(ws);            // 16MB [32768][256]
    u16* XLO   = (u16*)(ws + 16 * MB);  // 16MB
    u16* H1R   = (u16*)(ws + 32 * MB);  // 32MB [32768][512]
    u16* H1Lhi = (u16*)(ws + 64 * MB);  // 32MB
    u16* H1Llo = (u16*)(ws + 96 * MB);  // 32MB
    u16* H2R   = (u16*)(ws + 128 * MB); // 32MB
    u16* H2Lhi = (u16*)(ws);            // 32MB, aliases XHI+XLO (dead after ro L1)
    u16* H2Llo = (u16*)(ws + 32 * MB);  // 32MB, aliases H1R (dead after ro L2)
    float* WGT = (float*)(ws + 64 * MB);// 16MB, aliases H1Lhi (dead after lat L2)
    char* wb = ws + 160 * MB;
    u16* W1LThi = (u16*)(wb);               // 256KB [512][256]
    u16* W1LTlo = (u16*)(wb + 256 * KB);    // 256KB
    u16* W1RT   = (u16*)(wb + 512 * KB);    // 256KB
    u16* W2LThi = (u16*)(wb + 768 * KB);    // 512KB [512][512]
    u16* W2LTlo = (u16*)(wb + 1280 * KB);   // 512KB
    u16* W2RT   = (u16*)(wb + 1792 * KB);   // 512KB
    u16* W3LThi = (u16*)(wb + 2304 * KB);   // 128KB [128][512]
    u16* W3LTlo = (u16*)(wb + 2432 * KB);   // 128KB

    float* out_inv = (float*)d_out;                 // [32768][2]
    float* out_eq  = (float*)d_out + N_ATOMS * 2;   // [32768][4][3]

    const float s256 = 0.0625f;                 // 1/sqrt(256)
    const float s512 = 0.04419417382415922f;    // 1/sqrt(512)

    convx_kernel<<<dim3(4096), dim3(256), 0, stream>>>(inv, XHI, XLO);
    convw_kernel<<<dim3(3328), dim3(256), 0, stream>>>(w1l, w2l, w3l, w1r, w2r,
        W1LThi, W1LTlo, W1RT, W2LThi, W2LTlo, W2RT, W3LThi, W3LTlo);

    // lat L1 (split): [32768,256] -> H1L hi/lo (silu)
    gemm_multi<3, 4, true, 2><<<dim3(1024), dim3(256), 0, stream>>>(
        XHI, XLO, W1LThi, W1LTlo, H1Lhi, H1Llo, 512, 256, s256);
    // ro L1 (bf16): -> H1R (silu)
    gemm_multi<1, 4, true, 1><<<dim3(1024), dim3(256), 0, stream>>>(
        XHI, nullptr, W1RT, nullptr, H1R, nullptr, 512, 256, s256);
    // ro L2 (bf16): -> H2R (silu)   [must precede lat L2: H2Llo aliases H1R]
    gemm_multi<1, 4, true, 1><<<dim3(1024), dim3(256), 0, stream>>>(
        H1R, nullptr, W2RT, nullptr, H2R, nullptr, 512, 512, s512);
    // lat L2 (split): -> H2L hi/lo (silu)
    gemm_multi<3, 4, true, 2><<<dim3(1024), dim3(256), 0, stream>>>(
        H1Lhi, H1Llo, W2LThi, W2LTlo, H2Lhi, H2Llo, 512, 512, s512);
    // lat L3 (split): [32768,512] @ [512,128] -> WGT f32 (no act)
    gemm_multi<3, 1, false, 0><<<dim3(256), dim3(256), 0, stream>>>(
        H2Lhi, H2Llo, W3LThi, W3LTlo, WGT, nullptr, 128, 512, s512);
    // ro L3
    invout_kernel<<<dim3(8192), dim3(256), 0, stream>>>(H2R, w3r, out_inv);
    // equivariant epilogue
    eq_kernel<<<dim3(512), dim3(256), 0, stream>>>(eqf, WGT, typs, bond, out_eq);
}

// Round 4
// 204.960 us; speedup vs baseline: 1.1566x; 1.0559x over previous
//
#include <hip/hip_runtime.h>
#include <hip/hip_bf16.h>

#define N_ATOMS 32768

typedef __attribute__((ext_vector_type(4))) float f32x4;
typedef __attribute__((ext_vector_type(8))) short bf16x8;
typedef unsigned short u16;

__device__ __forceinline__ u16 f2b(float f) {
    union { __hip_bfloat16 b; u16 u; } c;
    c.b = __float2bfloat16(f);
    return c.u;
}
__device__ __forceinline__ float b2f(u16 u) {
    union { unsigned int i; float f; } c;
    c.i = ((unsigned int)u) << 16;
    return c.f;
}

#define GLDS16(src, dst) __builtin_amdgcn_global_load_lds( \
    (const __attribute__((address_space(1))) void*)(src),  \
    (__attribute__((address_space(3))) void*)(dst), 16, 0, 0)

// ---------------- conversion kernels ----------------

__global__ void convx_kernel(const float* __restrict__ x,
                             u16* __restrict__ xhi, u16* __restrict__ xlo) {
    size_t i = (size_t)(blockIdx.x * 256 + threadIdx.x) * 8;
    float4 v0 = *(const float4*)(x + i);
    float4 v1 = *(const float4*)(x + i + 4);
    float v[8] = {v0.x, v0.y, v0.z, v0.w, v1.x, v1.y, v1.z, v1.w};
    bf16x8 rh, rl;
#pragma unroll
    for (int j = 0; j < 8; ++j) {
        u16 h = f2b(v[j]);
        rh[j] = (short)h;
        rl[j] = (short)f2b(v[j] - b2f(h));
    }
    *(bf16x8*)(xhi + i) = rh;
    *(bf16x8*)(xlo + i) = rl;
}

__global__ void convw_kernel(const float* __restrict__ w1l, const float* __restrict__ w2l,
                             const float* __restrict__ w3l, const float* __restrict__ w1r,
                             const float* __restrict__ w2r,
                             u16* __restrict__ W1LThi, u16* __restrict__ W1LTlo,
                             u16* __restrict__ W1RT,
                             u16* __restrict__ W2LThi, u16* __restrict__ W2LTlo,
                             u16* __restrict__ W2RT,
                             u16* __restrict__ W3LThi, u16* __restrict__ W3LTlo) {
    int i = blockIdx.x * 256 + threadIdx.x;
    if (i < 131072) {                       // w1_lat [256,512] -> [512][256] hi/lo
        int n = i >> 8, k = i & 255;
        float v = w1l[k * 512 + n];
        u16 h = f2b(v);
        W1LThi[i] = h;
        W1LTlo[i] = f2b(v - b2f(h));
    } else if (i < 262144) {                // w1_ro -> [512][256] bf16
        int j = i - 131072;
        int n = j >> 8, k = j & 255;
        W1RT[j] = f2b(w1r[k * 512 + n]);
    } else if (i < 524288) {                // w2_lat [512,512] -> hi/lo
        int j = i - 262144;
        int n = j >> 9, k = j & 511;
        float v = w2l[k * 512 + n];
        u16 h = f2b(v);
        W2LThi[j] = h;
        W2LTlo[j] = f2b(v - b2f(h));
    } else if (i < 786432) {                // w2_ro -> bf16
        int j = i - 524288;
        int n = j >> 9, k = j & 511;
        W2RT[j] = f2b(w2r[k * 512 + n]);
    } else if (i < 851968) {                // w3_lat [512,128] -> [128][512] hi/lo
        int j = i - 786432;
        int n = j >> 9, k = j & 511;
        float v = w3l[k * 128 + n];
        u16 h = f2b(v);
        W3LThi[j] = h;
        W3LTlo[j] = f2b(v - b2f(h));
    }
}

// ---------------- 256x256 8-wave phase-split MFMA GEMM ----------------
// C = act( scale * sum_seg Aseg @ Bseg^T ).  BM=BN=256, BK=64, 512 threads,
// 8 waves as 2(M)x4(N), per-wave 128x64 output (acc[8][4]).  LDS 128KB dbuf
// -> 1 block/CU, grid = M/256 * N/256 (must be 256 here = all CUs).
// Per K-tile: 2 phases {12 ds_read_b128 | stage-half of next tile | lgkmcnt(0)
// | setprio(1) 32 MFMA setprio(0)}, then vmcnt(0)+barrier (1 barrier / 64 MFMA).
// NSEG=3: K-segments (Ahi,Bhi),(Alo,Bhi),(Ahi,Blo) = split-bf16 ~f32 precision.
// OUTK: 0 = f32, 1 = bf16, 2 = split hi/lo bf16.
template<int NSEG, int GX, bool SILU, int OUTK>
__global__ void __launch_bounds__(512, 2) gemm8p(
        const u16* __restrict__ Ahi, const u16* __restrict__ Alo,
        const u16* __restrict__ Bhi, const u16* __restrict__ Blo,
        void* __restrict__ Chi, void* __restrict__ Clo,
        int ldc, int K, float scale) {
    __shared__ __align__(16) u16 lA[2][256 * 64];   // 64KB
    __shared__ __align__(16) u16 lB[2][256 * 64];   // 64KB
    const int tid = threadIdx.x;
    const int lane = tid & 63;
    const int wid = tid >> 6;           // 0..7
    const int wm = wid >> 2;            // 0..1 -> 128-row half
    const int wn = wid & 3;             // 0..3 -> 64-col quarter
    const int rlane = lane & 15;
    const int kc = lane >> 4;           // 0..3
    const int cps = rlane & 7;          // row&7 == rlane&7 for all frag rows

    // bijective XCD swizzle (grid % 8 == 0)
    const int nwg = gridDim.x;
    const int bid = blockIdx.x;
    const int wg = (bid & 7) * (nwg >> 3) + (bid >> 3);
    const int bn = (wg % GX) * 256;
    const int bm = (wg / GX) * 256;

    const int kt = K >> 6;
    const int NT = NSEG * kt;

    const int srow = tid >> 3;          // 0..63
    const int scp = tid & 7;

    auto stageA = [&](int t, int buf) {
        int seg = (NSEG == 1) ? 0 : ((t >= kt) + (t >= 2 * kt));
        const u16* As = (NSEG == 1) ? Ahi : (seg == 1 ? Alo : Ahi);
        int k0 = (t - seg * kt) << 6;
        u16* la = lA[buf];
#pragma unroll
        for (int call = 0; call < 4; ++call) {
            int row = call * 64 + srow;
            int c = scp ^ (row & 7);    // pre-swizzled global source, linear LDS dest
            GLDS16(As + (size_t)(bm + row) * K + k0 + c * 8, la + (size_t)(row * 64 + scp * 8));
        }
    };
    auto stageB = [&](int t, int buf) {
        int seg = (NSEG == 1) ? 0 : ((t >= kt) + (t >= 2 * kt));
        const u16* Bs = (NSEG == 1) ? Bhi : (seg == 2 ? Blo : Bhi);
        int k0 = (t - seg * kt) << 6;
        u16* lb = lB[buf];
#pragma unroll
        for (int call = 0; call < 4; ++call) {
            int row = call * 64 + srow;
            int c = scp ^ (row & 7);
            GLDS16(Bs + (size_t)(bn + row) * K + k0 + c * 8, lb + (size_t)(row * 64 + scp * 8));
        }
    };

    f32x4 acc[8][4] = {};

    // prologue: tile 0 in flight, then sync
    stageA(0, 0);
    stageB(0, 0);
    asm volatile("s_waitcnt vmcnt(0)" ::: "memory");
    __builtin_amdgcn_s_barrier();

    for (int t = 0; t < NT; ++t) {
        const int cur = t & 1, nxt = cur ^ 1;
        const bool pf = (t + 1 < NT);
        const u16* la = lA[cur];
        const u16* lb = lB[cur];
#pragma unroll
        for (int ks = 0; ks < 2; ++ks) {
            bf16x8 af[8], bfr[4];
            const int cp = (ks * 4 + kc) ^ cps;
#pragma unroll
            for (int m = 0; m < 8; ++m) {
                int row = wm * 128 + m * 16 + rlane;
                af[m] = *(const bf16x8*)&la[row * 64 + cp * 8];
            }
#pragma unroll
            for (int n = 0; n < 4; ++n) {
                int row = wn * 64 + n * 16 + rlane;
                bfr[n] = *(const bf16x8*)&lb[row * 64 + cp * 8];
            }
            if (pf) {                       // issue next tile's loads early (stay in flight)
                if (ks == 0) stageA(t + 1, nxt);
                else         stageB(t + 1, nxt);
            }
            asm volatile("s_waitcnt lgkmcnt(0)" ::: "memory");
            __builtin_amdgcn_sched_barrier(0);
            __builtin_amdgcn_s_setprio(1);
#pragma unroll
            for (int m = 0; m < 8; ++m)
#pragma unroll
                for (int n = 0; n < 4; ++n)
                    acc[m][n] = __builtin_amdgcn_mfma_f32_16x16x32_bf16(af[m], bfr[n], acc[m][n], 0, 0, 0);
            __builtin_amdgcn_s_setprio(0);
        }
        asm volatile("s_waitcnt vmcnt(0)" ::: "memory");   // next tile's 8 loads landed
        __builtin_amdgcn_s_barrier();                      // all waves done reading cur
    }

    // epilogue: C/D layout col = lane&15, row = (lane>>4)*4 + reg
#pragma unroll
    for (int m = 0; m < 8; ++m) {
        int grow0 = bm + wm * 128 + m * 16 + ((lane >> 4) << 2);
#pragma unroll
        for (int n = 0; n < 4; ++n) {
            int gcol = bn + wn * 64 + n * 16 + rlane;
#pragma unroll
            for (int r = 0; r < 4; ++r) {
                float v = acc[m][n][r] * scale;
                if constexpr (SILU) v = v / (1.0f + __expf(-v));
                size_t idx = (size_t)(grow0 + r) * ldc + gcol;
                if constexpr (OUTK == 0) {
                    ((float*)Chi)[idx] = v;
                } else if constexpr (OUTK == 1) {
                    ((u16*)Chi)[idx] = f2b(v);
                } else {
                    u16 h = f2b(v);
                    ((u16*)Chi)[idx] = h;
                    ((u16*)Clo)[idx] = f2b(v - b2f(h));
                }
            }
        }
    }
}

// ---------------- 128x128 multi-segment GEMM (kept for L3: N=128) ----------------
template<int NSEG, int GX, bool SILU, int OUTK>
__global__ void __launch_bounds__(256, 2) gemm_multi(
        const u16* __restrict__ Ahi, const u16* __restrict__ Alo,
        const u16* __restrict__ Bhi, const u16* __restrict__ Blo,
        void* __restrict__ Chi, void* __restrict__ Clo,
        int ldc, int K, float scale) {
    __shared__ __align__(16) u16 lA[2][128 * 64];
    __shared__ __align__(16) u16 lB[2][128 * 64];
    const int tid = threadIdx.x;
    const int lane = tid & 63;
    const int wid = tid >> 6;
    const int wr = wid >> 1, wc = wid & 1;
    const int rlane = lane & 15;
    const int kc = lane >> 4;

    const int nwg = gridDim.x;
    const int bid = blockIdx.x;
    const int wg = (bid & 7) * (nwg >> 3) + (bid >> 3);
    const int bn = (wg % GX) * 128;
    const int bm = (wg / GX) * 128;

    const int kt = K >> 6;
    const int NT = NSEG * kt;

    auto stage = [&](int t, int buf) {
        int seg = (NSEG == 1) ? 0 : ((t >= kt) + (t >= 2 * kt));
        const u16* As = (NSEG == 1) ? Ahi : (seg == 1 ? Alo : Ahi);
        const u16* Bs = (NSEG == 1) ? Bhi : (seg == 2 ? Blo : Bhi);
        int k0 = (t - seg * kt) << 6;
        u16* la = lA[buf];
        u16* lb = lB[buf];
#pragma unroll
        for (int call = 0; call < 4; ++call) {
            int id = call * 256 + tid;
            int row = id >> 3, cp = id & 7;
            int c = cp ^ (row & 7);
            GLDS16(As + (size_t)(bm + row) * K + k0 + c * 8, la + id * 8);
            GLDS16(Bs + (size_t)(bn + row) * K + k0 + c * 8, lb + id * 8);
        }
    };

    f32x4 acc[4][4] = {};

    auto compute = [&](int buf) {
        const u16* la = lA[buf];
        const u16* lb = lB[buf];
        bf16x8 af[2][4], bfr[2][4];
#pragma unroll
        for (int ks = 0; ks < 2; ++ks) {
#pragma unroll
            for (int m = 0; m < 4; ++m) {
                int row = wr * 64 + m * 16 + rlane;
                int cp = (ks * 4 + kc) ^ (row & 7);
                af[ks][m] = *(const bf16x8*)&la[row * 64 + cp * 8];
            }
#pragma unroll
            for (int n = 0; n < 4; ++n) {
                int row = wc * 64 + n * 16 + rlane;
                int cp = (ks * 4 + kc) ^ (row & 7);
                bfr[ks][n] = *(const bf16x8*)&lb[row * 64 + cp * 8];
            }
        }
#pragma unroll
        for (int m = 0; m < 4; ++m)
#pragma unroll
            for (int n = 0; n < 4; ++n) {
                acc[m][n] = __builtin_amdgcn_mfma_f32_16x16x32_bf16(af[0][m], bfr[0][n], acc[m][n], 0, 0, 0);
                acc[m][n] = __builtin_amdgcn_mfma_f32_16x16x32_bf16(af[1][m], bfr[1][n], acc[m][n], 0, 0, 0);
            }
    };

    stage(0, 0);
    for (int t = 0; t < NT - 1; ++t) {
        __builtin_amdgcn_s_barrier();
        stage(t + 1, (t + 1) & 1);
        __builtin_amdgcn_sched_barrier(0);
        asm volatile("s_waitcnt vmcnt(8)" ::: "memory");
        __builtin_amdgcn_s_barrier();
        __builtin_amdgcn_sched_barrier(0);
        compute(t & 1);
    }
    asm volatile("s_waitcnt vmcnt(0)" ::: "memory");
    __builtin_amdgcn_s_barrier();
    __builtin_amdgcn_sched_barrier(0);
    compute((NT - 1) & 1);

#pragma unroll
    for (int m = 0; m < 4; ++m) {
        int grow0 = bm + wr * 64 + m * 16 + ((lane >> 4) << 2);
#pragma unroll
        for (int n = 0; n < 4; ++n) {
            int gcol = bn + wc * 64 + n * 16 + rlane;
#pragma unroll
            for (int r = 0; r < 4; ++r) {
                float v = acc[m][n][r] * scale;
                if constexpr (SILU) v = v / (1.0f + __expf(-v));
                size_t idx = (size_t)(grow0 + r) * ldc + gcol;
                if constexpr (OUTK == 0) {
                    ((float*)Chi)[idx] = v;
                } else if constexpr (OUTK == 1) {
                    ((u16*)Chi)[idx] = f2b(v);
                } else {
                    u16 h = f2b(v);
                    ((u16*)Chi)[idx] = h;
                    ((u16*)Clo)[idx] = f2b(v - b2f(h));
                }
            }
        }
    }
}

// ---------------- inv_out: H2R [32768,512] bf16 @ w3_ro [512,2] f32 ----------------
__global__ void invout_kernel(const u16* __restrict__ H2b,
                              const float* __restrict__ w3,
                              float* __restrict__ out) {
    int g = blockIdx.x * 256 + threadIdx.x;
    int n = g >> 6;
    int lane = g & 63;
    bf16x8 hv = *(const bf16x8*)(H2b + (size_t)n * 512 + lane * 8);
    float s0 = 0.f, s1 = 0.f;
#pragma unroll
    for (int j = 0; j < 8; ++j) {
        float hf = b2f((u16)hv[j]);
        int k = lane * 8 + j;
        s0 = fmaf(hf, w3[2 * k], s0);
        s1 = fmaf(hf, w3[2 * k + 1], s1);
    }
#pragma unroll
    for (int off = 32; off > 0; off >>= 1) {
        s0 += __shfl_xor(s0, off);
        s1 += __shfl_xor(s1, off);
    }
    if (lane == 0) {
        const float s = 0.04419417382415922f;   // 1/sqrt(512)
        out[2 * n] = s0 * s;
        out[2 * n + 1] = s1 * s;
    }
}

// ---------------- per-atom equivariant output ----------------
__global__ void eq_kernel(const float* __restrict__ eqf, const float* __restrict__ wgt,
                          const int* __restrict__ types, const float* __restrict__ bond,
                          float* __restrict__ out) {
    int t = blockIdx.x * 256 + threadIdx.x;   // 131072 = 32768*4
    int n = t >> 2, v = t & 3;
    const float* e = eqf + (size_t)n * 96;
    const float* w = wgt + (size_t)n * 128 + v;
    float a0 = 0.f, a1 = 0.f, a2 = 0.f;
#pragma unroll
    for (int u = 0; u < 32; ++u) {
        float wv = w[u * 4];
        a0 = fmaf(e[u * 3 + 0], wv, a0);
        a1 = fmaf(e[u * 3 + 1], wv, a1);
        a2 = fmaf(e[u * 3 + 2], wv, a2);
    }
    const float s = 0.17677669529663687f;   // 1/sqrt(32)
    a0 *= s; a1 *= s; a2 *= s;
    float norm = sqrtf(a0 * a0 + a1 * a1 + a2 * a2) + 1e-10f;
    float bl = bond[types[n] * 4 + v];
    float r0 = a0 / norm, r1 = a1 / norm, r2 = a2 / norm;
    if (isnan(r0)) r0 = 0.f;
    if (isnan(r1)) r1 = 0.f;
    if (isnan(r2)) r2 = 0.f;
    out[(size_t)n * 12 + v * 3 + 0] = r0 * bl;
    out[(size_t)n * 12 + v * 3 + 1] = r1 * bl;
    out[(size_t)n * 12 + v * 3 + 2] = r2 * bl;
}

// ---------------- launcher ----------------
extern "C" void kernel_launch(void* const* d_in, const int* in_sizes, int n_in,
                              void* d_out, int out_size, void* d_ws, size_t ws_size,
                              hipStream_t stream) {
    const float* inv  = (const float*)d_in[0];
    const float* eqf  = (const float*)d_in[1];
    const int*   typs = (const int*)d_in[2];
    const float* w1l  = (const float*)d_in[3];
    const float* w2l  = (const float*)d_in[4];
    const float* w3l  = (const float*)d_in[5];
    const float* w1r  = (const float*)d_in[6];
    const float* w2r  = (const float*)d_in[7];
    const float* w3r  = (const float*)d_in[8];
    const float* bond = (const float*)d_in[9];

    char* ws = (char*)d_ws;
    const size_t MB = 1024 * 1024, KB = 1024;
    // live-range-aliased memory map:
    u16* XHI   = (u16*)(ws);            // 16MB [32768][256]
    u16* XLO   = (u16*)(ws + 16 * MB);  // 16MB
    u16* H1R   = (u16*)(ws + 32 * MB);  // 32MB [32768][512]
    u16* H1Lhi = (u16*)(ws + 64 * MB);  // 32MB
    u16* H1Llo = (u16*)(ws + 96 * MB);  // 32MB
    u16* H2R   = (u16*)(ws + 128 * MB); // 32MB
    u16* H2Lhi = (u16*)(ws);            // 32MB, aliases XHI+XLO (dead after ro L1)
    u16* H2Llo = (u16*)(ws + 32 * MB);  // 32MB, aliases H1R (dead after ro L2)
    float* WGT = (float*)(ws + 64 * MB);// 16MB, aliases H1Lhi (dead after lat L2)
    char* wb = ws + 160 * MB;
    u16* W1LThi = (u16*)(wb);               // 256KB [512][256]
    u16* W1LTlo = (u16*)(wb + 256 * KB);    // 256KB
    u16* W1RT   = (u16*)(wb + 512 * KB);    // 256KB
    u16* W2LThi = (u16*)(wb + 768 * KB);    // 512KB [512][512]
    u16* W2LTlo = (u16*)(wb + 1280 * KB);   // 512KB
    u16* W2RT   = (u16*)(wb + 1792 * KB);   // 512KB
    u16* W3LThi = (u16*)(wb + 2304 * KB);   // 128KB [128][512]
    u16* W3LTlo = (u16*)(wb + 2432 * KB);   // 128KB

    float* out_inv = (float*)d_out;                 // [32768][2]
    float* out_eq  = (float*)d_out + N_ATOMS * 2;   // [32768][4][3]

    const float s256 = 0.0625f;                 // 1/sqrt(256)
    const float s512 = 0.04419417382415922f;    // 1/sqrt(512)

    convx_kernel<<<dim3(4096), dim3(256), 0, stream>>>(inv, XHI, XLO);
    convw_kernel<<<dim3(3328), dim3(256), 0, stream>>>(w1l, w2l, w3l, w1r, w2r,
        W1LThi, W1LTlo, W1RT, W2LThi, W2LTlo, W2RT, W3LThi, W3LTlo);

    // lat L1 (split): [32768,256] -> H1L hi/lo (silu)       grid 128x2 = 256
    gemm8p<3, 2, true, 2><<<dim3(256), dim3(512), 0, stream>>>(
        XHI, XLO, W1LThi, W1LTlo, H1Lhi, H1Llo, 512, 256, s256);
    // ro L1 (bf16): -> H1R (silu)
    gemm8p<1, 2, true, 1><<<dim3(256), dim3(512), 0, stream>>>(
        XHI, nullptr, W1RT, nullptr, H1R, nullptr, 512, 256, s256);
    // ro L2 (bf16): -> H2R (silu)   [must precede lat L2: H2Llo aliases H1R]
    gemm8p<1, 2, true, 1><<<dim3(256), dim3(512), 0, stream>>>(
        H1R, nullptr, W2RT, nullptr, H2R, nullptr, 512, 512, s512);
    // lat L2 (split): -> H2L hi/lo (silu)
    gemm8p<3, 2, true, 2><<<dim3(256), dim3(512), 0, stream>>>(
        H1Lhi, H1Llo, W2LThi, W2LTlo, H2Lhi, H2Llo, 512, 512, s512);
    // lat L3 (split): [32768,512] @ [512,128] -> WGT f32 (no act)  (N=128: 128^2 kernel)
    gemm_multi<3, 1, false, 0><<<dim3(256), dim3(256), 0, stream>>>(
        H2Lhi, H2Llo, W3LThi, W3LTlo, WGT, nullptr, 128, 512, s512);
    // ro L3
    invout_kernel<<<dim3(8192), dim3(256), 0, stream>>>(H2R, w3r, out_inv);
    // equivariant epilogue
    eq_kernel<<<dim3(512), dim3(256), 0, stream>>>(eqf, WGT, typs, bond, out_eq);
}